// Round 1
// baseline (561.557 us; speedup 1.0000x reference)
//
#include <hip/hip_runtime.h>
#include <hip/hip_bf16.h>

#define B_ROWS 4096
#define D_K    256
#define Q_ROWS 65536
#define HALF   2048

typedef __bf16 bf16x8 __attribute__((ext_vector_type(8)));
typedef float  f32x4  __attribute__((ext_vector_type(4)));
typedef const __attribute__((address_space(1))) void* gptr1;
typedef __attribute__((address_space(3))) void* lptr3;

__device__ __forceinline__ unsigned int f32_ordered(float f) {
    unsigned int u = __float_as_uint(f);
    return (u & 0x80000000u) ? ~u : (u | 0x80000000u);
}

__device__ __forceinline__ unsigned short f2bf_rn(float f) {
    unsigned int u = __float_as_uint(f);
    u += 0x7FFFu + ((u >> 16) & 1u);
    return (unsigned short)(u >> 16);
}

// ---------- f32 -> bf16 (RNE), 4 elems/thread ----------
__global__ __launch_bounds__(256) void cvt_bf16_kernel(const float* __restrict__ in,
                                                       unsigned short* __restrict__ out,
                                                       int n4) {
    int i = blockIdx.x * 256 + threadIdx.x;
    if (i >= n4) return;
    float4 v = ((const float4*)in)[i];
    ushort4 o;
    o.x = f2bf_rn(v.x); o.y = f2bf_rn(v.y); o.z = f2bf_rn(v.z); o.w = f2bf_rn(v.w);
    ((ushort4*)out)[i] = o;
}

// ---------- zero argmax array ----------
__global__ __launch_bounds__(256) void init_amax_kernel(unsigned long long* amax) {
    int i = blockIdx.x * 256 + threadIdx.x;
    if (i < B_ROWS) amax[i] = 0ull;  // ordered-float 0 == below every real value
}

// ---------- fused sim GEMM + row argmax ----------
// A: 4096x256 bf16 (emb), B: 65536x256 bf16 (queue), amax: packed (ordered_val<<32)|~col
#define BM 128
#define BN 128
#define BK 32
__global__ __launch_bounds__(256) void sim_argmax_kernel(const unsigned short* __restrict__ A,
                                                         const unsigned short* __restrict__ Bq,
                                                         unsigned long long* __restrict__ amax) {
    __shared__ unsigned short As[BM * BK];   // row-major, K contiguous (NO padding: global_load_lds)
    __shared__ unsigned short Bs[BN * BK];

    const int tid  = threadIdx.x;
    const int wave = tid >> 6;
    const int lane = tid & 63;
    const int l15  = lane & 15;
    const int quad = lane >> 4;
    const int blk_m = blockIdx.x * BM;   // x fastest: concurrent blocks share the B n-tile
    const int blk_n = blockIdx.y * BN;
    const int wave_m = (wave >> 1) * 64;
    const int wave_n = (wave & 1) * 64;

    // staging: chunk q = wave*2+j covers LDS bytes [q*1024, q*1024+1024); lane i -> byte q*1024+i*16
    const int srow  = lane >> 2;        // 0..15 within chunk
    const int skoff = (lane & 3) * 8;   // element offset in K

    f32x4 acc[4][4];
#pragma unroll
    for (int i = 0; i < 4; i++)
#pragma unroll
        for (int j = 0; j < 4; j++) acc[i][j] = (f32x4){0.f, 0.f, 0.f, 0.f};

    for (int kb = 0; kb < D_K; kb += BK) {
#pragma unroll
        for (int j = 0; j < 2; j++) {
            int q = wave * 2 + j;
            int row = q * 16 + srow;
            const unsigned short* ga = A  + (size_t)(blk_m + row) * D_K + kb + skoff;
            const unsigned short* gb = Bq + (size_t)(blk_n + row) * D_K + kb + skoff;
            __builtin_amdgcn_global_load_lds((gptr1)ga, (lptr3)&As[q * 16 * BK], 16, 0, 0);
            __builtin_amdgcn_global_load_lds((gptr1)gb, (lptr3)&Bs[q * 16 * BK], 16, 0, 0);
        }
        __syncthreads();

        bf16x8 a_frag[4], b_frag[4];
#pragma unroll
        for (int mi = 0; mi < 4; mi++)
            a_frag[mi] = *(const bf16x8*)&As[(wave_m + mi * 16 + l15) * BK + quad * 8];
#pragma unroll
        for (int ni = 0; ni < 4; ni++)
            b_frag[ni] = *(const bf16x8*)&Bs[(wave_n + ni * 16 + l15) * BK + quad * 8];
#pragma unroll
        for (int mi = 0; mi < 4; mi++)
#pragma unroll
            for (int ni = 0; ni < 4; ni++)
                acc[mi][ni] = __builtin_amdgcn_mfma_f32_16x16x32_bf16(a_frag[mi], b_frag[ni],
                                                                      acc[mi][ni], 0, 0, 0);
        __syncthreads();
    }

    // Epilogue: per lane, element (mi,ni,reg) = row wave_m+mi*16+quad*4+reg, col wave_n+ni*16+l15
#pragma unroll
    for (int mi = 0; mi < 4; mi++) {
#pragma unroll
        for (int reg = 0; reg < 4; reg++) {
            float bv = acc[mi][0][reg];
            int   bc = blk_n + wave_n + l15;
#pragma unroll
            for (int ni = 1; ni < 4; ni++) {
                float v = acc[mi][ni][reg];
                int   c = blk_n + wave_n + ni * 16 + l15;
                if (v > bv) { bv = v; bc = c; }
            }
            unsigned long long key =
                ((unsigned long long)f32_ordered(bv) << 32) |
                (unsigned long long)(0xFFFFFFFFu - (unsigned)bc);   // ~col: ties -> smaller col
#pragma unroll
            for (int m = 1; m < 16; m <<= 1) {
                unsigned long long o = __shfl_xor(key, m, 16);
                if (o > key) key = o;
            }
            if (l15 == mi * 4 + reg) {  // spread the 16 atomics across the 16 lanes of the group
                int row = blk_m + wave_m + mi * 16 + quad * 4 + reg;
                atomicMax(&amax[row], key);
            }
        }
    }
}

// ---------- gather nearest rows (bf16) ----------
__global__ __launch_bounds__(64) void gather_kernel(const unsigned long long* __restrict__ amax,
                                                    const unsigned short* __restrict__ queue_bf,
                                                    unsigned short* __restrict__ nearest_bf) {
    int row = blockIdx.x;
    unsigned idx = 0xFFFFFFFFu - (unsigned)(amax[row] & 0xFFFFFFFFull);
    const ushort4* src = (const ushort4*)(queue_bf + (size_t)idx * D_K);
    ushort4* dst = (ushort4*)(nearest_bf + (size_t)row * D_K);
    dst[threadIdx.x] = src[threadIdx.x];   // 64 lanes x 8B = 512B = full row
}

// ---------- logits + online logsumexp - diag ----------
// one wave per 16 rows; rows 0..2047 = nn_a vs preds_b, rows 2048..4095 = nn_b vs preds_a
__global__ __launch_bounds__(64) void logits_ce_kernel(const unsigned short* __restrict__ nearest_bf,
                                                       const unsigned short* __restrict__ preds_bf,
                                                       float* __restrict__ row_loss) {
    const int gw   = blockIdx.x;        // 0..255
    const int lane = threadIdx.x;
    const int l15  = lane & 15;
    const int quad = lane >> 4;
    const int h    = gw >> 7;           // 0: ab, 1: ba
    const int rowbase = gw * 16;        // global row base
    const unsigned short* Bbase = preds_bf + (size_t)((1 - h) * HALF) * D_K;

    bf16x8 a[8];
#pragma unroll
    for (int kc = 0; kc < 8; kc++)
        a[kc] = *(const bf16x8*)&nearest_bf[(size_t)(rowbase + l15) * D_K + kc * 32 + quad * 8];

    float m_run[4], l_run[4], diag[4];
#pragma unroll
    for (int r = 0; r < 4; r++) { m_run[r] = -1e30f; l_run[r] = 0.f; diag[r] = -1e30f; }

    const int tdiag = gw & 127;
    for (int t = 0; t < 128; t++) {
        f32x4 acc = (f32x4){0.f, 0.f, 0.f, 0.f};
#pragma unroll
        for (int kc = 0; kc < 8; kc++) {
            bf16x8 b = *(const bf16x8*)&Bbase[(size_t)(t * 16 + l15) * D_K + kc * 32 + quad * 8];
            acc = __builtin_amdgcn_mfma_f32_16x16x32_bf16(a[kc], b, acc, 0, 0, 0);
        }
#pragma unroll
        for (int reg = 0; reg < 4; reg++) {
            float v = acc[reg] * 10.0f;              // 1/TEMPERATURE
            int mrow = quad * 4 + reg;
            if (t == tdiag && l15 == mrow) diag[reg] = v;
            float nm = fmaxf(m_run[reg], v);
            l_run[reg] = l_run[reg] * __expf(m_run[reg] - nm) + __expf(v - nm);
            m_run[reg] = nm;
        }
    }
#pragma unroll
    for (int reg = 0; reg < 4; reg++) {
#pragma unroll
        for (int m = 1; m < 16; m <<= 1) {
            float om = __shfl_xor(m_run[reg], m, 16);
            float ol = __shfl_xor(l_run[reg], m, 16);
            float od = __shfl_xor(diag[reg], m, 16);
            float nm = fmaxf(m_run[reg], om);
            l_run[reg] = l_run[reg] * __expf(m_run[reg] - nm) + ol * __expf(om - nm);
            m_run[reg] = nm;
            diag[reg] = fmaxf(diag[reg], od);
        }
        if (l15 == 0) {
            int row = rowbase + quad * 4 + reg;
            row_loss[row] = (m_run[reg] + __logf(l_run[reg])) - diag[reg];
        }
    }
}

// ---------- final scalar reduce ----------
__global__ __launch_bounds__(256) void reduce_kernel(const float* __restrict__ row_loss,
                                                     float* __restrict__ out) {
    __shared__ float sdata[4];
    float s = 0.f;
    for (int i = threadIdx.x; i < B_ROWS; i += 256) s += row_loss[i];
#pragma unroll
    for (int m = 1; m < 64; m <<= 1) s += __shfl_xor(s, m, 64);
    if ((threadIdx.x & 63) == 0) sdata[threadIdx.x >> 6] = s;
    __syncthreads();
    if (threadIdx.x == 0)
        out[0] = (sdata[0] + sdata[1] + sdata[2] + sdata[3]) / (float)B_ROWS;
}

extern "C" void kernel_launch(void* const* d_in, const int* in_sizes, int n_in,
                              void* d_out, int out_size, void* d_ws, size_t ws_size,
                              hipStream_t stream) {
    const float* emb   = (const float*)d_in[0];
    const float* preds = (const float*)d_in[1];
    const float* queue = (const float*)d_in[2];

    char* w = (char*)d_ws;
    unsigned long long* amax   = (unsigned long long*)w;            // 32 KB
    float*          row_loss   = (float*)(w + (32 << 10));          // 16 KB
    unsigned short* emb_bf     = (unsigned short*)(w + (64 << 10));         // 2 MB
    unsigned short* preds_bf   = (unsigned short*)(w + (64 << 10) + (2u << 20));      // 2 MB
    unsigned short* queue_bf   = (unsigned short*)(w + (64 << 10) + (4u << 20));      // 32 MB
    unsigned short* nearest_bf = (unsigned short*)(w + (64 << 10) + (36u << 20));     // 2 MB

    cvt_bf16_kernel<<<dim3((B_ROWS * D_K / 4) / 256), 256, 0, stream>>>(emb, emb_bf, B_ROWS * D_K / 4);
    cvt_bf16_kernel<<<dim3((B_ROWS * D_K / 4) / 256), 256, 0, stream>>>(preds, preds_bf, B_ROWS * D_K / 4);
    cvt_bf16_kernel<<<dim3((Q_ROWS * D_K / 4) / 256), 256, 0, stream>>>(queue, queue_bf, Q_ROWS * D_K / 4);
    init_amax_kernel<<<dim3(B_ROWS / 256), 256, 0, stream>>>(amax);
    sim_argmax_kernel<<<dim3(B_ROWS / BM, Q_ROWS / BN), 256, 0, stream>>>(emb_bf, queue_bf, amax);
    gather_kernel<<<dim3(B_ROWS), 64, 0, stream>>>(amax, queue_bf, nearest_bf);
    logits_ce_kernel<<<dim3(B_ROWS / 16), 64, 0, stream>>>(nearest_bf, preds_bf, row_loss);
    reduce_kernel<<<dim3(1), 256, 0, stream>>>(row_loss, (float*)d_out);
}

// Round 2
// 356.899 us; speedup vs baseline: 1.5734x; 1.5734x over previous
//
#include <hip/hip_runtime.h>
#include <hip/hip_bf16.h>

#define B_ROWS 4096
#define D_K    256
#define Q_ROWS 65536
#define HALF   2048

typedef __bf16 bf16x8 __attribute__((ext_vector_type(8)));
typedef float  f32x4  __attribute__((ext_vector_type(4)));
typedef const __attribute__((address_space(1))) void* gptr1;
typedef __attribute__((address_space(3))) void* lptr3;

__device__ __forceinline__ unsigned int f32_ordered(float f) {
    unsigned int u = __float_as_uint(f);
    return (u & 0x80000000u) ? ~u : (u | 0x80000000u);
}

__device__ __forceinline__ unsigned short f2bf_rn(float f) {
    unsigned int u = __float_as_uint(f);
    u += 0x7FFFu + ((u >> 16) & 1u);
    return (unsigned short)(u >> 16);
}

// ---------- f32 -> bf16 (RNE), 4 elems/thread ----------
__global__ __launch_bounds__(256) void cvt_bf16_kernel(const float* __restrict__ in,
                                                       unsigned short* __restrict__ out,
                                                       int n4) {
    int i = blockIdx.x * 256 + threadIdx.x;
    if (i >= n4) return;
    float4 v = ((const float4*)in)[i];
    ushort4 o;
    o.x = f2bf_rn(v.x); o.y = f2bf_rn(v.y); o.z = f2bf_rn(v.z); o.w = f2bf_rn(v.w);
    ((ushort4*)out)[i] = o;
}

// ---------- zero argmax array ----------
__global__ __launch_bounds__(256) void init_amax_kernel(unsigned long long* amax) {
    int i = blockIdx.x * 256 + threadIdx.x;
    if (i < B_ROWS) amax[i] = 0ull;  // ordered-float 0 == below every real value
}

// ---------- fused sim GEMM + row argmax ----------
// A: 4096x256 bf16 (emb), B: 65536x256 bf16 (queue), amax: packed (ordered_val<<32)|~col
// Each block: 128 rows x (NCHUNK*128) cols. Running argmax in registers across
// n-chunks; ONE shuffle-reduce + atomic per slot per block (epilogue amortized 8x).
#define BM 128
#define BN 128
#define BK 32
#define NCHUNK 8
__global__ __launch_bounds__(256) void sim_argmax_kernel(const unsigned short* __restrict__ A,
                                                         const unsigned short* __restrict__ Bq,
                                                         unsigned long long* __restrict__ amax) {
    __shared__ unsigned short As[BM * BK];   // row-major, K contiguous (NO padding: global_load_lds)
    __shared__ unsigned short Bs[BN * BK];

    const int tid  = threadIdx.x;
    const int wave = tid >> 6;
    const int lane = tid & 63;
    const int l15  = lane & 15;
    const int quad = lane >> 4;
    const int blk_m = blockIdx.x * BM;              // x fastest: m-blocks share the B n-tile via L2/LLC
    const int nbase = blockIdx.y * (BN * NCHUNK);
    const int wave_m = (wave >> 1) * 64;
    const int wave_n = (wave & 1) * 64;

    // staging: chunk q = wave*2+j covers LDS bytes [q*1024, q*1024+1024); lane i -> byte q*1024+i*16
    const int srow  = lane >> 2;        // 0..15 within chunk
    const int skoff = (lane & 3) * 8;   // element offset in K

    float bestv[4][4];
    int   bestc[4][4];
#pragma unroll
    for (int mi = 0; mi < 4; mi++)
#pragma unroll
        for (int reg = 0; reg < 4; reg++) { bestv[mi][reg] = -1e30f; bestc[mi][reg] = 0; }

#pragma unroll 1
    for (int nc = 0; nc < NCHUNK; nc++) {
        const int blk_n = nbase + nc * BN;

        f32x4 acc[4][4];
#pragma unroll
        for (int i = 0; i < 4; i++)
#pragma unroll
            for (int j = 0; j < 4; j++) acc[i][j] = (f32x4){0.f, 0.f, 0.f, 0.f};

        for (int kb = 0; kb < D_K; kb += BK) {
#pragma unroll
            for (int j = 0; j < 2; j++) {
                int q = wave * 2 + j;
                int row = q * 16 + srow;
                const unsigned short* ga = A  + (size_t)(blk_m + row) * D_K + kb + skoff;
                const unsigned short* gb = Bq + (size_t)(blk_n + row) * D_K + kb + skoff;
                __builtin_amdgcn_global_load_lds((gptr1)ga, (lptr3)&As[q * 16 * BK], 16, 0, 0);
                __builtin_amdgcn_global_load_lds((gptr1)gb, (lptr3)&Bs[q * 16 * BK], 16, 0, 0);
            }
            __syncthreads();

            bf16x8 a_frag[4], b_frag[4];
#pragma unroll
            for (int mi = 0; mi < 4; mi++)
                a_frag[mi] = *(const bf16x8*)&As[(wave_m + mi * 16 + l15) * BK + quad * 8];
#pragma unroll
            for (int ni = 0; ni < 4; ni++)
                b_frag[ni] = *(const bf16x8*)&Bs[(wave_n + ni * 16 + l15) * BK + quad * 8];
#pragma unroll
            for (int mi = 0; mi < 4; mi++)
#pragma unroll
                for (int ni = 0; ni < 4; ni++)
                    acc[mi][ni] = __builtin_amdgcn_mfma_f32_16x16x32_bf16(a_frag[mi], b_frag[ni],
                                                                          acc[mi][ni], 0, 0, 0);
            __syncthreads();
        }

        // fold this n-chunk into the running per-slot best (registers only)
        const int col0 = blk_n + wave_n + l15;
#pragma unroll
        for (int mi = 0; mi < 4; mi++) {
#pragma unroll
            for (int reg = 0; reg < 4; reg++) {
#pragma unroll
                for (int ni = 0; ni < 4; ni++) {
                    float v = acc[mi][ni][reg];
                    int   c = col0 + ni * 16;
                    if (v > bestv[mi][reg]) { bestv[mi][reg] = v; bestc[mi][reg] = c; }
                }
            }
        }
    }

    // Epilogue (once per block): pack, 16-lane reduce, one atomic per slot
#pragma unroll
    for (int mi = 0; mi < 4; mi++) {
#pragma unroll
        for (int reg = 0; reg < 4; reg++) {
            unsigned long long key =
                ((unsigned long long)f32_ordered(bestv[mi][reg]) << 32) |
                (unsigned long long)(0xFFFFFFFFu - (unsigned)bestc[mi][reg]);   // ~col: ties -> smaller col
#pragma unroll
            for (int m = 1; m < 16; m <<= 1) {
                unsigned long long o = __shfl_xor(key, m, 16);
                if (o > key) key = o;
            }
            if (l15 == mi * 4 + reg) {  // spread the 16 atomics across the 16 lanes of the group
                int row = blk_m + wave_m + mi * 16 + quad * 4 + reg;
                atomicMax(&amax[row], key);
            }
        }
    }
}

// ---------- gather nearest rows (bf16) ----------
__global__ __launch_bounds__(64) void gather_kernel(const unsigned long long* __restrict__ amax,
                                                    const unsigned short* __restrict__ queue_bf,
                                                    unsigned short* __restrict__ nearest_bf) {
    int row = blockIdx.x;
    unsigned idx = 0xFFFFFFFFu - (unsigned)(amax[row] & 0xFFFFFFFFull);
    const ushort4* src = (const ushort4*)(queue_bf + (size_t)idx * D_K);
    ushort4* dst = (ushort4*)(nearest_bf + (size_t)row * D_K);
    dst[threadIdx.x] = src[threadIdx.x];   // 64 lanes x 8B = 512B = full row
}

// ---------- logits + online logsumexp - diag ----------
// one block (4 waves) per 16 rows; waves split the 128 column-tiles 32 each,
// partial (m,l,diag) merged through LDS.
__global__ __launch_bounds__(256) void logits_ce_kernel(const unsigned short* __restrict__ nearest_bf,
                                                        const unsigned short* __restrict__ preds_bf,
                                                        float* __restrict__ row_loss) {
    const int gw   = blockIdx.x;        // 0..255 (16-row group)
    const int tid  = threadIdx.x;
    const int wave = tid >> 6;          // 0..3
    const int lane = tid & 63;
    const int l15  = lane & 15;
    const int quad = lane >> 4;
    const int h    = gw >> 7;           // 0: ab, 1: ba
    const int rowbase = gw * 16;        // global row base
    const unsigned short* Bbase = preds_bf + (size_t)((1 - h) * HALF) * D_K;

    __shared__ float sm[4][16], sl[4][16], sd[4][16];

    bf16x8 a[8];
#pragma unroll
    for (int kc = 0; kc < 8; kc++)
        a[kc] = *(const bf16x8*)&nearest_bf[(size_t)(rowbase + l15) * D_K + kc * 32 + quad * 8];

    float m_run[4], l_run[4], diag[4];
#pragma unroll
    for (int r = 0; r < 4; r++) { m_run[r] = -1e30f; l_run[r] = 0.f; diag[r] = -1e30f; }

    const int tdiag = gw & 127;
    for (int tt = 0; tt < 32; tt++) {
        const int t = wave * 32 + tt;
        f32x4 acc = (f32x4){0.f, 0.f, 0.f, 0.f};
#pragma unroll
        for (int kc = 0; kc < 8; kc++) {
            bf16x8 b = *(const bf16x8*)&Bbase[(size_t)(t * 16 + l15) * D_K + kc * 32 + quad * 8];
            acc = __builtin_amdgcn_mfma_f32_16x16x32_bf16(a[kc], b, acc, 0, 0, 0);
        }
#pragma unroll
        for (int reg = 0; reg < 4; reg++) {
            float v = acc[reg] * 10.0f;              // 1/TEMPERATURE
            int mrow = quad * 4 + reg;
            if (t == tdiag && l15 == mrow) diag[reg] = v;
            float nm = fmaxf(m_run[reg], v);
            l_run[reg] = l_run[reg] * __expf(m_run[reg] - nm) + __expf(v - nm);
            m_run[reg] = nm;
        }
    }
    // 16-lane merge within the wave
#pragma unroll
    for (int reg = 0; reg < 4; reg++) {
#pragma unroll
        for (int m = 1; m < 16; m <<= 1) {
            float om = __shfl_xor(m_run[reg], m, 16);
            float ol = __shfl_xor(l_run[reg], m, 16);
            float od = __shfl_xor(diag[reg], m, 16);
            float nm = fmaxf(m_run[reg], om);
            l_run[reg] = l_run[reg] * __expf(m_run[reg] - nm) + ol * __expf(om - nm);
            m_run[reg] = nm;
            diag[reg] = fmaxf(diag[reg], od);
        }
        if (l15 == 0) {
            sm[wave][quad * 4 + reg] = m_run[reg];
            sl[wave][quad * 4 + reg] = l_run[reg];
            sd[wave][quad * 4 + reg] = diag[reg];
        }
    }
    __syncthreads();
    // cross-wave merge: thread r (0..15) owns row rowbase+r
    if (tid < 16) {
        float M = -1e30f, L = 0.f, Dg = -1e30f;
#pragma unroll
        for (int w = 0; w < 4; w++) {
            float mw = sm[w][tid], lw = sl[w][tid], dw = sd[w][tid];
            float nM = fmaxf(M, mw);
            L = L * __expf(M - nM) + lw * __expf(mw - nM);
            M = nM;
            Dg = fmaxf(Dg, dw);
        }
        row_loss[rowbase + tid] = (M + __logf(L)) - Dg;
    }
}

// ---------- final scalar reduce ----------
__global__ __launch_bounds__(256) void reduce_kernel(const float* __restrict__ row_loss,
                                                     float* __restrict__ out) {
    __shared__ float sdata[4];
    float s = 0.f;
    for (int i = threadIdx.x; i < B_ROWS; i += 256) s += row_loss[i];
#pragma unroll
    for (int m = 1; m < 64; m <<= 1) s += __shfl_xor(s, m, 64);
    if ((threadIdx.x & 63) == 0) sdata[threadIdx.x >> 6] = s;
    __syncthreads();
    if (threadIdx.x == 0)
        out[0] = (sdata[0] + sdata[1] + sdata[2] + sdata[3]) / (float)B_ROWS;
}

extern "C" void kernel_launch(void* const* d_in, const int* in_sizes, int n_in,
                              void* d_out, int out_size, void* d_ws, size_t ws_size,
                              hipStream_t stream) {
    const float* emb   = (const float*)d_in[0];
    const float* preds = (const float*)d_in[1];
    const float* queue = (const float*)d_in[2];

    char* w = (char*)d_ws;
    unsigned long long* amax   = (unsigned long long*)w;            // 32 KB
    float*          row_loss   = (float*)(w + (32 << 10));          // 16 KB
    unsigned short* emb_bf     = (unsigned short*)(w + (64 << 10));         // 2 MB
    unsigned short* preds_bf   = (unsigned short*)(w + (64 << 10) + (2u << 20));      // 2 MB
    unsigned short* queue_bf   = (unsigned short*)(w + (64 << 10) + (4u << 20));      // 32 MB
    unsigned short* nearest_bf = (unsigned short*)(w + (64 << 10) + (36u << 20));     // 2 MB

    cvt_bf16_kernel<<<dim3((B_ROWS * D_K / 4) / 256), 256, 0, stream>>>(emb, emb_bf, B_ROWS * D_K / 4);
    cvt_bf16_kernel<<<dim3((B_ROWS * D_K / 4) / 256), 256, 0, stream>>>(preds, preds_bf, B_ROWS * D_K / 4);
    cvt_bf16_kernel<<<dim3((Q_ROWS * D_K / 4) / 256), 256, 0, stream>>>(queue, queue_bf, Q_ROWS * D_K / 4);
    init_amax_kernel<<<dim3(B_ROWS / 256), 256, 0, stream>>>(amax);
    sim_argmax_kernel<<<dim3(B_ROWS / BM, Q_ROWS / (BN * NCHUNK)), 256, 0, stream>>>(emb_bf, queue_bf, amax);
    gather_kernel<<<dim3(B_ROWS), 64, 0, stream>>>(amax, queue_bf, nearest_bf);
    logits_ce_kernel<<<dim3(B_ROWS / 16), 256, 0, stream>>>(nearest_bf, preds_bf, row_loss);
    reduce_kernel<<<dim3(1), 256, 0, stream>>>(row_loss, (float*)d_out);
}